// Round 1
// baseline (12.585 us; speedup 1.0000x reference)
//
#include <hip/hip_runtime.h>
#include <math.h>

// SplineNetwork: cubic-convolution (Keys) spline interpolation on a regular
// 256x256 control grid over [-1,1]^2.
//
// The reference's brute-force 16-NN on a REGULAR grid is (up to conv-zero
// terms) exactly the 4x4 cell block around the query:
//  - cubic_conv(s) == 0 for |s| >= 2 (strict masks; f2 has roots at 1 and 2),
//    so every grid point outside the 4x4 block contributes 0.
//  - When the true 16-NN swaps a far block-corner for an outside point, the
//    outside point contributes exactly 0 and the dropped corner's conv is
//    <= ~1.5e-3 (bounded by 0.25*fx^2*fy^2 under the exclusion constraint),
//    well inside the 2e-2 absmax threshold.
//
// Output layout (tuple concatenated flat): out[0..B) = spline values,
// out[B..3B) = copy of x.

__device__ __forceinline__ float cubic_conv(float a) {
    // a = |s| >= 0. Matches reference's piecewise masks exactly at a=1,2
    // (both polynomials evaluate to 0 there).
    if (a < 1.0f) {
        return ((1.5f * a - 2.5f) * a) * a + 1.0f;
    }
    if (a < 2.0f) {
        return ((-0.5f * a + 2.5f) * a - 4.0f) * a + 2.0f;
    }
    return 0.0f;
}

__global__ void spline_eval_kernel(const float* __restrict__ x,
                                   const float* __restrict__ cp,
                                   const float* __restrict__ w,
                                   float* __restrict__ out,
                                   int B, int N) {
    int b = blockIdx.x * blockDim.x + threadIdx.x;
    if (b >= B) return;

    float qx = x[2 * b + 0];
    float qy = x[2 * b + 1];

    // Grid origin and spacing read from the actual control points (row 0
    // holds x-coords t[j]; column stride N holds y-coords t[i]).
    float t0x = cp[0];                 // t[0] (== -1)
    float t0y = cp[1];
    float hx  = cp[2] - cp[0];         // t[1] - t[0], same as reference h_x
    float hy  = cp[2 * N + 1] - cp[1]; // reference h_y

    float ux = (qx - t0x) / hx;        // grid coordinate in [0, N-1]
    float uy = (qy - t0y) / hy;
    int ix0 = (int)floorf(ux);
    int iy0 = (int)floorf(uy);

    float acc = 0.0f;
#pragma unroll
    for (int dy = -1; dy <= 2; ++dy) {
        int iy = iy0 + dy;
        if (iy < 0 || iy >= N) continue;
        // y-coordinate of grid row iy: control_points[iy*N + 0].y
        float cyv = cp[(iy * N) * 2 + 1];
        float wy = cubic_conv(fabsf((qy - cyv) / hy));
        if (wy == 0.0f) continue;
#pragma unroll
        for (int dx = -1; dx <= 2; ++dx) {
            int ix = ix0 + dx;
            if (ix < 0 || ix >= N) continue;
            // x-coordinate of grid column ix: control_points[ix].x
            float cxv = cp[ix * 2 + 0];
            float wx = cubic_conv(fabsf((qx - cxv) / hx));
            acc += w[iy * N + ix] * (wx * wy);
        }
    }

    out[b] = acc;
    // Second tuple element: x passed through verbatim.
    out[B + 2 * b + 0] = qx;
    out[B + 2 * b + 1] = qy;
}

extern "C" void kernel_launch(void* const* d_in, const int* in_sizes, int n_in,
                              void* d_out, int out_size, void* d_ws, size_t ws_size,
                              hipStream_t stream) {
    const float* x  = (const float*)d_in[0];  // (B, 2)
    const float* cp = (const float*)d_in[1];  // (N*N, 2)
    const float* w  = (const float*)d_in[2];  // (N*N, 1)
    float* out = (float*)d_out;

    int B = in_sizes[0] / 2;
    int NN = in_sizes[1] / 2;
    int N = (int)(sqrtf((float)NN) + 0.5f);

    int block = 256;
    int grid = (B + block - 1) / block;
    spline_eval_kernel<<<grid, block, 0, stream>>>(x, cp, w, out, B, N);
}

// Round 2
// 9.687 us; speedup vs baseline: 1.2991x; 1.2991x over previous
//
#include <hip/hip_runtime.h>
#include <math.h>

// SplineNetwork: Keys cubic-convolution interpolation on a regular 256x256
// grid over [-1,1]^2. The reference's brute-force 16-NN on a regular grid
// reduces (up to conv-zero terms, bounded ~1.5e-3 * |w| at block corners) to
// the separable 4x4 stencil around the query cell.
//
// This version removes all control-point gathers: on a uniform grid the
// conv argument for tap ix is exactly (u - ix) where u = (q - t0)/h, so the
// four 1-D weights come from the fractional part alone. Both cubic pieces
// agree (==0) at |s|=1,2, so fixed-branch evaluation matches the reference's
// strict masks.
//
// Remaining memory work per thread: 1 float2 query load (coalesced),
// 16 weight gathers (4 rows x 4 consecutive floats, 256 KB array ->
// L2/L3-resident), 1 scalar + 1 float2 store.
//
// Output tuple flat: out[0..B) = spline value, out[B..3B) = x verbatim.

__device__ __forceinline__ float cc_inner(float a) {
    // Keys kernel, |s| in [0,1]: 1.5a^3 - 2.5a^2 + 1
    return ((1.5f * a - 2.5f) * a) * a + 1.0f;
}
__device__ __forceinline__ float cc_outer(float a) {
    // Keys kernel, |s| in [1,2]: -0.5a^3 + 2.5a^2 - 4a + 2
    return ((-0.5f * a + 2.5f) * a - 4.0f) * a + 2.0f;
}

__global__ void __launch_bounds__(64)
spline_eval_kernel(const float* __restrict__ x,
                   const float* __restrict__ cp,
                   const float* __restrict__ w,
                   float* __restrict__ out,
                   int B, int N) {
    int b = blockIdx.x * blockDim.x + threadIdx.x;
    if (b >= B) return;

    float2 q = ((const float2*)x)[b];

    // Grid origin/spacing from the actual control points (wave-uniform
    // broadcast loads). Matches reference h_x, h_y definitions.
    float t0x = cp[0];
    float t0y = cp[1];
    float hx  = cp[2] - cp[0];
    float hy  = cp[2 * N + 1] - cp[1];

    float ux = (q.x - t0x) / hx;   // grid coordinate in [0, N-1)
    float uy = (q.y - t0y) / hy;
    float fx0 = floorf(ux);
    float fy0 = floorf(uy);
    int ix0 = (int)fx0;
    int iy0 = (int)fy0;
    float fx = ux - fx0;           // in [0,1)
    float fy = uy - fy0;

    // Separable 1-D stencil weights for taps {ix0-1, ix0, ix0+1, ix0+2}:
    // |s| = {1+f, f, 1-f, 2-f} respectively.
    float wxs[4] = { cc_outer(1.0f + fx), cc_inner(fx),
                     cc_inner(1.0f - fx), cc_outer(2.0f - fx) };
    float wys[4] = { cc_outer(1.0f + fy), cc_inner(fy),
                     cc_inner(1.0f - fy), cc_outer(2.0f - fy) };

    float acc = 0.0f;
#pragma unroll
    for (int dy = 0; dy < 4; ++dy) {
        int iy = iy0 + dy - 1;
        if ((unsigned)iy >= (unsigned)N) continue;   // outside grid: no point exists
        const float* row = w + iy * N;
        float rs = 0.0f;
#pragma unroll
        for (int dx = 0; dx < 4; ++dx) {
            int ix = ix0 + dx - 1;
            if ((unsigned)ix >= (unsigned)N) continue;
            rs = fmaf(wxs[dx], row[ix], rs);
        }
        acc = fmaf(wys[dy], rs, acc);
    }

    out[b] = acc;
    ((float2*)(out + B))[b] = q;   // second tuple element: x passthrough
}

extern "C" void kernel_launch(void* const* d_in, const int* in_sizes, int n_in,
                              void* d_out, int out_size, void* d_ws, size_t ws_size,
                              hipStream_t stream) {
    const float* x  = (const float*)d_in[0];  // (B, 2)
    const float* cp = (const float*)d_in[1];  // (N*N, 2)
    const float* w  = (const float*)d_in[2];  // (N*N, 1)
    float* out = (float*)d_out;

    int B = in_sizes[0] / 2;
    int NN = in_sizes[1] / 2;
    int N = (int)(sqrtf((float)NN) + 0.5f);

    // 64-thread blocks -> 64 workgroups -> spread the latency-bound weight
    // gathers across ~64 CUs instead of 16.
    int block = 64;
    int grid = (B + block - 1) / block;
    spline_eval_kernel<<<grid, block, 0, stream>>>(x, cp, w, out, B, N);
}